// Round 4
// baseline (78396.350 us; speedup 1.0000x reference)
//
#include <hip/hip_runtime.h>
#include <hip/hip_cooperative_groups.h>
#include <math.h>

namespace cg = cooperative_groups;

// B=128, E=512, D=512, V=275, HW=24 -> P=576, T=300
static constexpr int Bn  = 128;
static constexpr int En  = 512;
static constexpr int Dn  = 512;
static constexpr int Vn  = 275;
static constexpr int Pn  = 576;
static constexpr int Tn  = 300;
static constexpr int TM1 = 299;

static constexpr int NTHR = 512;   // 8 waves per WG

typedef unsigned short ushort_t;
typedef unsigned int uint_t;

__device__ __forceinline__ float fast_tanh(float x) {
    float e2 = __expf(2.0f * x);
    return 1.0f - 2.0f / (e2 + 1.0f);
}
__device__ __forceinline__ float sigmoidf_(float x) {
    return 1.0f / (1.0f + __expf(-x));
}
__device__ __forceinline__ float wave_reduce(float v) {
#pragma unroll
    for (int o = 32; o > 0; o >>= 1) v += __shfl_xor(v, o, 64);
    return v;
}
__device__ __forceinline__ ushort_t f2b(float x) {      // fp32 -> bf16 RNE
    uint_t u = __float_as_uint(x);
    u = (u + 0x7fffu + ((u >> 16) & 1u)) >> 16;
    return (ushort_t)u;
}
__device__ __forceinline__ float b2f(ushort_t u) {
    return __uint_as_float(((uint_t)u) << 16);
}
__device__ __forceinline__ void unpack8(uint4 q, float* f) {  // 8 bf16 (little-endian pairs)
    f[0] = __uint_as_float(q.x << 16); f[1] = __uint_as_float(q.x & 0xffff0000u);
    f[2] = __uint_as_float(q.y << 16); f[3] = __uint_as_float(q.y & 0xffff0000u);
    f[4] = __uint_as_float(q.z << 16); f[5] = __uint_as_float(q.z & 0xffff0000u);
    f[6] = __uint_as_float(q.w << 16); f[7] = __uint_as_float(q.w & 0xffff0000u);
}

// phase-B row: acc = sum_{8} tanh(Ws + hU) * v   (per-lane partial)
__device__ __forceinline__ float brow_acc(uint4 q, float4 h0, float4 h1,
                                          float4 v0, float4 v1) {
    float w8[8]; unpack8(q, w8);
    float acc;
    acc  = fast_tanh(w8[0] + h0.x) * v0.x;
    acc += fast_tanh(w8[1] + h0.y) * v0.y;
    acc += fast_tanh(w8[2] + h0.z) * v0.z;
    acc += fast_tanh(w8[3] + h0.w) * v0.w;
    acc += fast_tanh(w8[4] + h1.x) * v1.x;
    acc += fast_tanh(w8[5] + h1.y) * v1.y;
    acc += fast_tanh(w8[6] + h1.z) * v1.z;
    acc += fast_tanh(w8[7] + h1.w) * v1.w;
    return acc;
}

// phase-D row: per-lane partial of ctx dot
__device__ __forceinline__ float crow_acc(uint4 q, float tl,
                                          float4 a0, float4 a1, float at) {
    float w8[8]; unpack8(q, w8);
    float s;
    s  = w8[0] * a0.x + w8[1] * a0.y + w8[2] * a0.z + w8[3] * a0.w;
    s += w8[4] * a1.x + w8[5] * a1.y + w8[6] * a1.z + w8[7] * a1.w;
    s += tl * at;
    return s;
}

// ---------------- one-time kernels (unchanged) ----------------

__global__ void mean_kernel(const float* __restrict__ feats, float* __restrict__ mean) {
    int w = blockIdx.x * 4 + (threadIdx.x >> 6);   // row in [0, B*E)
    int lane = threadIdx.x & 63;
    const float* row = feats + (size_t)w * Pn;
    float s = 0.f;
#pragma unroll
    for (int i = 0; i < 9; i++) s += row[lane + i * 64];
    s = wave_reduce(s);
    if (lane == 0) mean[w] = s * (1.0f / Pn);
}

__global__ void init_kernel(const float* __restrict__ mean,
                            const float* __restrict__ ihw, const float* __restrict__ ihb,
                            const float* __restrict__ icw, const float* __restrict__ icb,
                            float* __restrict__ h, float* __restrict__ c) {
    int b = blockIdx.x; int d = threadIdx.x;  // 512 threads
    const float* m = mean + b * En;
    float ah = ihb[d], ac = icb[d];
#pragma unroll 8
    for (int e = 0; e < En; e++) {
        float mv = m[e];
        ah += mv * ihw[e * Dn + d];
        ac += mv * icw[e * Dn + d];
    }
    h[b * Dn + d] = ah;
    c[b * Dn + d] = ac;
}

// Ws[b,p,d] = sum_e feats[b,e,p] * W_w[e,d] + W_b[d]  -> bf16
__global__ void ws_kernel(const float* __restrict__ feats, const float* __restrict__ Ww,
                          const float* __restrict__ Wb, ushort_t* __restrict__ WsH) {
    int p = blockIdx.x, b = blockIdx.y, d = threadIdx.x;  // 512 threads
    const float* f = feats + (size_t)b * En * Pn + p;
    float acc = Wb[d];
#pragma unroll 8
    for (int e = 0; e < En; e++) acc += f[(size_t)e * Pn] * Ww[e * Dn + d];
    WsH[((size_t)b * Pn + p) * Dn + d] = f2b(acc);
}

__global__ void declen_kernel(const int* __restrict__ lengths, float* __restrict__ out_declen) {
    int b = threadIdx.x;
    if (b < Bn) out_declen[b] = (float)(lengths[b] - 1);
}

// fp32 -> bf16 straight copy
__global__ void cvt_kernel(const float* __restrict__ src, ushort_t* __restrict__ dst, int n) {
    int idx = blockIdx.x * 256 + threadIdx.x;
    if (idx < n) dst[idx] = f2b(src[idx]);
}

// transpose + cvt: src[rows][cols] fp32 -> dst[cols][rows] bf16
__global__ void cvtT_kernel(const float* __restrict__ src, ushort_t* __restrict__ dst,
                            int rows, int cols) {
    int idx = blockIdx.x * 256 + threadIdx.x;
    if (idx >= rows * cols) return;
    int r = idx / cols, c = idx - r * cols;
    dst[(size_t)c * rows + r] = f2b(src[idx]);
}

// ---------------- persistent cooperative loop kernel ----------------

struct LoopParams {
    const ushort_t* WsH;
    const ushort_t* featsH;
    const ushort_t* wihH;
    const ushort_t* whhH;
    const ushort_t* UwTh;
    const ushort_t* fbwTh;
    const ushort_t* fcwTh;
    const float* Ub;  const float* fbb; const float* fcb;
    const float* vw;  const float* vb;
    const float* bih; const float* bhh;
    const float* emb;
    const int* captions; const int* lengths;
    float* hA; float* hB; float* cbuf;
    float* hU; float* gate; float* xctx; float* esc;
    float* out_preds; float* out_alphas;
};

template <int NWG_>
__global__
__attribute__((amdgpu_flat_work_group_size(NTHR, NTHR), amdgpu_waves_per_eu(4, 4)))
void loop_kernel(LoopParams p) {
    constexpr int NWAVES_ = NWG_ * (NTHR / 64);    // 2048 or 4096
    constexpr int WPB_B   = NWAVES_ / Bn;          // phase-B waves per b: 16 or 32
    constexpr int PPW     = Pn / WPB_B;            // p per wave: 36 or 18 (both %3==0)
    constexpr int WGPB    = NWG_ / Bn;             // phase-C/D WGs per b: 2 or 4
    constexpr int ROWS    = En / WGPB;             // e-rows per WG: 256 or 128
    constexpr int NIT     = ROWS / 8;              // ctx iters: 32 or 16 (even)
    constexpr int NPAIRS  = Bn / 2;                // 64 b-pairs
    constexpr int WPP     = NWAVES_ / NPAIRS;      // phase-E waves per pair: 32 or 64
    constexpr int DPW     = Dn / WPP;              // d per wave: 16 or 8

    cg::grid_group grid = cg::this_grid();
    const int tid  = threadIdx.x;
    const int lane = tid & 63;
    const int wwg  = tid >> 6;                   // wave in WG [0,8)
    const int wg   = blockIdx.x;                 // [0,NWG_)
    const int wv   = wg * (NTHR / 64) + wwg;     // global wave [0,NWAVES_)

    __shared__ float s_alpha[Pn];
    __shared__ float s_red[16];

    for (int tau = 0; tau <= TM1; ++tau) {
        const float* hin  = (tau & 1) ? p.hB : p.hA;
        float*       hout = (tau & 1) ? p.hA : p.hB;

        // ---- phase A: hU = h@U, gate = sigmoid(h@f_beta), preds(t=tau-1) = h@fc ----
        {
            const float4* h4 = (const float4*)hin;
            for (int it = wv; it < 32 * 325; it += NWAVES_) {
                int bg = it / 325, jg = it - bg * 325;
                int j0 = jg * 4;
                if (tau == 0 && j0 >= 1024) continue;   // no preds at first step
                if (tau == TM1 && j0 < 1024) continue;  // final pass: preds only
                float4 hv[4][2];
#pragma unroll
                for (int i = 0; i < 4; i++) {
                    int basei = (bg * 4 + i) * 128 + 2 * lane;
                    hv[i][0] = h4[basei]; hv[i][1] = h4[basei + 1];
                }
#pragma unroll
                for (int jj = 0; jj < 4; jj++) {
                    int j = j0 + jj;
                    const ushort_t* row;
                    if (j < 512) row = p.UwTh + (size_t)j * 512;
                    else if (j < 1024) row = p.fbwTh + (size_t)(j - 512) * 512;
                    else { if (j - 1024 >= Vn) continue; row = p.fcwTh + (size_t)(j - 1024) * 512; }
                    uint4 q = *(const uint4*)(row + 8 * lane);
                    float w8[8]; unpack8(q, w8);
                    float a[4];
#pragma unroll
                    for (int i = 0; i < 4; i++) {
                        a[i] = hv[i][0].x * w8[0] + hv[i][0].y * w8[1] + hv[i][0].z * w8[2] + hv[i][0].w * w8[3]
                             + hv[i][1].x * w8[4] + hv[i][1].y * w8[5] + hv[i][1].z * w8[6] + hv[i][1].w * w8[7];
                    }
#pragma unroll
                    for (int o = 32; o > 0; o >>= 1) {
#pragma unroll
                        for (int i = 0; i < 4; i++) a[i] += __shfl_xor(a[i], o, 64);
                    }
                    if (lane == 0) {
                        if (j < 512) {
                            float bias = p.Ub[j];
#pragma unroll
                            for (int i = 0; i < 4; i++) p.hU[(bg * 4 + i) * Dn + j] = a[i] + bias;
                        } else if (j < 1024) {
                            int e = j - 512;
                            float bias = p.fbb[e];
#pragma unroll
                            for (int i = 0; i < 4; i++) p.gate[(bg * 4 + i) * En + e] = sigmoidf_(a[i] + bias);
                        } else if (tau > 0) {
                            int v = j - 1024;
                            int t = tau - 1;
                            float bias = p.fcb[v];
#pragma unroll
                            for (int i = 0; i < 4; i++) {
                                int b = bg * 4 + i;
                                int dec = p.lengths[b] - 1;
                                p.out_preds[((size_t)b * TM1 + t) * Vn + v] = (t < dec) ? (a[i] + bias) : 0.f;
                            }
                        }
                    }
                }
            }
        }
        if (tau == TM1) break;
        grid.sync();

        // ---- phase B: e[b,p] = sum_d tanh(Ws + hU)*v + vb ----
        // wave -> (b, PPW consecutive p). hU/v hoisted; depth-3 rolling prefetch.
        {
            int b  = wv / WPB_B;
            int p0 = (wv % WPB_B) * PPW;
            const float4* hu4 = (const float4*)(p.hU + (b << 9));
            float4 h0 = hu4[2 * lane], h1 = hu4[2 * lane + 1];
            const float4* v4 = (const float4*)p.vw;
            float4 vv0 = v4[2 * lane], vv1 = v4[2 * lane + 1];
            float vb0 = p.vb[0];
            const ushort_t* base = p.WsH + ((size_t)b * Pn + p0) * Dn + 8 * lane;
            uint4 qa = *(const uint4*)(base);
            uint4 qb = *(const uint4*)(base + Dn);
            uint4 qc = *(const uint4*)(base + 2 * Dn);
            for (int k0 = 0; k0 < PPW; k0 += 3) {
                uint4 na = qa, nb = qb, nc = qc;
                if (k0 + 3 < PPW) {
                    na = *(const uint4*)(base + (size_t)(k0 + 3) * Dn);
                    nb = *(const uint4*)(base + (size_t)(k0 + 4) * Dn);
                    nc = *(const uint4*)(base + (size_t)(k0 + 5) * Dn);
                }
                float a0 = wave_reduce(brow_acc(qa, h0, h1, vv0, vv1));
                float a1 = wave_reduce(brow_acc(qb, h0, h1, vv0, vv1));
                float a2 = wave_reduce(brow_acc(qc, h0, h1, vv0, vv1));
                if (lane == 0) {
                    p.esc[b * Pn + p0 + k0]     = a0 + vb0;
                    p.esc[b * Pn + p0 + k0 + 1] = a1 + vb0;
                    p.esc[b * Pn + p0 + k0 + 2] = a2 + vb0;
                }
                qa = na; qb = nb; qc = nc;
            }
        }
        grid.sync();

        // ---- phase C+D: softmax(alpha in LDS) + ctx, WGPB WGs per b ----
        {
            int b = wg / WGPB, part = wg % WGPB;
            float v0 = p.esc[b * Pn + tid];
            float v1 = (tid < 64) ? p.esc[b * Pn + 512 + tid] : -3.0e38f;
            float m = fmaxf(v0, v1);
#pragma unroll
            for (int o = 32; o > 0; o >>= 1) m = fmaxf(m, __shfl_xor(m, o, 64));
            if (lane == 0) s_red[wwg] = m;
            __syncthreads();
            if (tid == 0) {
                float mm = s_red[0];
                for (int i = 1; i < 8; i++) mm = fmaxf(mm, s_red[i]);
                s_red[8] = mm;
            }
            __syncthreads();
            float mx  = s_red[8];
            float ex0 = __expf(v0 - mx);
            float ex1 = (tid < 64) ? __expf(v1 - mx) : 0.f;
            float ssum = wave_reduce(ex0 + ex1);
            if (lane == 0) s_red[wwg] = ssum;
            __syncthreads();
            if (tid == 0) {
                float ss = 0.f;
                for (int i = 0; i < 8; i++) ss += s_red[i];
                s_red[9] = 1.0f / ss;
            }
            __syncthreads();
            float inv = s_red[9];
            float a0 = ex0 * inv;
            float a1 = ex1 * inv;
            s_alpha[tid] = a0;
            if (tid < 64) s_alpha[512 + tid] = a1;
            if (part == 0) {
                int dec = p.lengths[b] - 1;
                float keep = (tau < dec) ? 1.f : 0.f;
                size_t rb = ((size_t)b * TM1 + tau) * Pn;
                p.out_alphas[rb + tid] = a0 * keep;
                if (tid < 64) p.out_alphas[rb + 512 + tid] = a1 * keep;
            }
            __syncthreads();
            // ctx rows: each WG does ROWS e-rows of its b; depth-2 rolling prefetch
            const float4* a4 = (const float4*)s_alpha;
            float4 aa0 = a4[2 * lane], aa1 = a4[2 * lane + 1];
            float atail = s_alpha[512 + lane];
            int e0 = part * ROWS + wwg;
            const ushort_t* fbase = p.featsH + ((size_t)(b * En + e0)) * Pn;
            uint4 qa = *(const uint4*)(fbase + 8 * lane);
            float ta = b2f(fbase[512 + lane]);
            uint4 qb = *(const uint4*)(fbase + 8 * Pn + 8 * lane);
            float tb = b2f(fbase[8 * Pn + 512 + lane]);
            for (int i = 0; i < NIT; i += 2) {
                uint4 na = qa, nb = qb; float tna = ta, tnb = tb;
                if (i + 2 < NIT) {
                    const ushort_t* fn = fbase + (size_t)(i + 2) * 8 * Pn;
                    na  = *(const uint4*)(fn + 8 * lane);
                    tna = b2f(fn[512 + lane]);
                    nb  = *(const uint4*)(fn + 8 * Pn + 8 * lane);
                    tnb = b2f(fn[8 * Pn + 512 + lane]);
                }
                float s0 = wave_reduce(crow_acc(qa, ta, aa0, aa1, atail));
                float s1 = wave_reduce(crow_acc(qb, tb, aa0, aa1, atail));
                if (lane == 0) {
                    int e = e0 + i * 8;
                    p.xctx[b * En + e]     = p.gate[b * En + e] * s0;
                    p.xctx[b * En + e + 8] = p.gate[b * En + e + 8] * s1;
                }
                qa = na; qb = nb; ta = tna; tb = tnb;
            }
        }
        grid.sync();

        // ---- phase E: LSTM cell. Wave owns (b-pair, DPW consecutive d).
        // Activations (2 b's) live in registers; weights stream per-d. ----
        {
            int bp = wv / WPP;            // [0,64)
            int d0 = (wv % WPP) * DPW;
            float4 u[2][6];   // per batch: emb0,emb1, gctx0,gctx1, h0,h1
#pragma unroll
            for (int i = 0; i < 2; i++) {
                int b = bp * 2 + i;
                int tok = p.captions[b * Tn + tau];
                const float4* e4 = (const float4*)(p.emb + (size_t)tok * Dn);
                const float4* x4 = (const float4*)(p.xctx + b * En);
                const float4* h4 = (const float4*)(hin + b * Dn);
                u[i][0] = e4[2 * lane]; u[i][1] = e4[2 * lane + 1];
                u[i][2] = x4[2 * lane]; u[i][3] = x4[2 * lane + 1];
                u[i][4] = h4[2 * lane]; u[i][5] = h4[2 * lane + 1];
            }
            for (int dd = 0; dd < DPW; ++dd) {
                int d = d0 + dd;
                float acc[4][2];
#pragma unroll
                for (int g = 0; g < 4; g++)
#pragma unroll
                    for (int i = 0; i < 2; i++) acc[g][i] = 0.f;
#pragma unroll
                for (int g = 0; g < 4; g++) {
                    int j = g * 512 + d;
                    const ushort_t* wi = p.wihH + (size_t)j * 1024;
                    const ushort_t* wh = p.whhH + (size_t)j * 512;
                    uint4 q0 = *(const uint4*)(wi + 8 * lane);
                    uint4 q1 = *(const uint4*)(wi + 512 + 8 * lane);
                    uint4 q2 = *(const uint4*)(wh + 8 * lane);
                    float wa[8], wb[8], wc[8];
                    unpack8(q0, wa); unpack8(q1, wb); unpack8(q2, wc);
#pragma unroll
                    for (int i = 0; i < 2; i++) {
                        float s;
                        s  = u[i][0].x * wa[0] + u[i][0].y * wa[1] + u[i][0].z * wa[2] + u[i][0].w * wa[3];
                        s += u[i][1].x * wa[4] + u[i][1].y * wa[5] + u[i][1].z * wa[6] + u[i][1].w * wa[7];
                        s += u[i][2].x * wb[0] + u[i][2].y * wb[1] + u[i][2].z * wb[2] + u[i][2].w * wb[3];
                        s += u[i][3].x * wb[4] + u[i][3].y * wb[5] + u[i][3].z * wb[6] + u[i][3].w * wb[7];
                        s += u[i][4].x * wc[0] + u[i][4].y * wc[1] + u[i][4].z * wc[2] + u[i][4].w * wc[3];
                        s += u[i][5].x * wc[4] + u[i][5].y * wc[5] + u[i][5].z * wc[6] + u[i][5].w * wc[7];
                        acc[g][i] += s;
                    }
                }
#pragma unroll
                for (int o = 32; o > 0; o >>= 1) {
#pragma unroll
                    for (int g = 0; g < 4; g++)
#pragma unroll
                        for (int i = 0; i < 2; i++) acc[g][i] += __shfl_xor(acc[g][i], o, 64);
                }
                if (lane == 0) {
                    float bi  = p.bih[d] + p.bhh[d];
                    float bf  = p.bih[512 + d] + p.bhh[512 + d];
                    float bgg = p.bih[1024 + d] + p.bhh[1024 + d];
                    float bo  = p.bih[1536 + d] + p.bhh[1536 + d];
#pragma unroll
                    for (int i = 0; i < 2; i++) {
                        int b = bp * 2 + i;
                        float ig = sigmoidf_(acc[0][i] + bi);
                        float fg = sigmoidf_(acc[1][i] + bf);
                        float gg = fast_tanh(acc[2][i] + bgg);
                        float og = sigmoidf_(acc[3][i] + bo);
                        float cn = fg * p.cbuf[b * Dn + d] + ig * gg;
                        p.cbuf[b * Dn + d] = cn;
                        hout[b * Dn + d] = og * fast_tanh(cn);
                    }
                }
            }
        }
        grid.sync();
    }
}

extern "C" void kernel_launch(void* const* d_in, const int* in_sizes, int n_in,
                              void* d_out, int out_size, void* d_ws, size_t ws_size,
                              hipStream_t stream) {
    const float* feats    = (const float*)d_in[0];
    const int*   captions = (const int*)d_in[1];
    const int*   lengths  = (const int*)d_in[2];
    const float* U_w      = (const float*)d_in[3];
    const float* U_b      = (const float*)d_in[4];
    const float* W_w      = (const float*)d_in[5];
    const float* W_b      = (const float*)d_in[6];
    const float* v_w      = (const float*)d_in[7];
    const float* v_b      = (const float*)d_in[8];
    const float* init_h_w = (const float*)d_in[9];
    const float* init_h_b = (const float*)d_in[10];
    const float* init_c_w = (const float*)d_in[11];
    const float* init_c_b = (const float*)d_in[12];
    const float* f_beta_w = (const float*)d_in[13];
    const float* f_beta_b = (const float*)d_in[14];
    const float* fc_w     = (const float*)d_in[15];
    const float* fc_b     = (const float*)d_in[16];
    const float* emb      = (const float*)d_in[17];
    const float* lstm_w_ih = (const float*)d_in[18];
    const float* lstm_w_hh = (const float*)d_in[19];
    const float* lstm_b_ih = (const float*)d_in[20];
    const float* lstm_b_hh = (const float*)d_in[21];

    char* base = (char*)d_ws;
    size_t off = 0;
    ushort_t* WsH    = (ushort_t*)(base + off); off += (size_t)Bn * Pn * Dn * 2;   // 75.5 MB
    ushort_t* featsH = (ushort_t*)(base + off); off += (size_t)Bn * En * Pn * 2;   // 75.5 MB
    ushort_t* wihH   = (ushort_t*)(base + off); off += (size_t)4 * Dn * (Dn + En) * 2;
    ushort_t* whhH   = (ushort_t*)(base + off); off += (size_t)4 * Dn * Dn * 2;
    ushort_t* UwTh   = (ushort_t*)(base + off); off += (size_t)Dn * Dn * 2;
    ushort_t* fbwTh  = (ushort_t*)(base + off); off += (size_t)En * Dn * 2;
    ushort_t* fcwTh  = (ushort_t*)(base + off); off += (size_t)Vn * Dn * 2;
    float* mean  = (float*)(base + off); off += (size_t)Bn * En * 4;
    float* hA    = (float*)(base + off); off += (size_t)Bn * Dn * 4;
    float* hB    = (float*)(base + off); off += (size_t)Bn * Dn * 4;
    float* cbuf  = (float*)(base + off); off += (size_t)Bn * Dn * 4;
    float* hU    = (float*)(base + off); off += (size_t)Bn * Dn * 4;
    float* gate  = (float*)(base + off); off += (size_t)Bn * En * 4;
    float* xctx  = (float*)(base + off); off += (size_t)Bn * En * 4;
    float* esc   = (float*)(base + off); off += (size_t)Bn * Pn * 4;

    float* out_preds  = (float*)d_out;
    float* out_alphas = out_preds + (size_t)Bn * TM1 * Vn;
    float* out_declen = out_alphas + (size_t)Bn * TM1 * Pn;

    // ---- one-time precompute ----
    mean_kernel<<<Bn * En / 4, 256, 0, stream>>>(feats, mean);
    init_kernel<<<Bn, 512, 0, stream>>>(mean, init_h_w, init_h_b, init_c_w, init_c_b, hA, cbuf);
    ws_kernel<<<dim3(Pn, Bn), 512, 0, stream>>>(feats, W_w, W_b, WsH);
    declen_kernel<<<1, 128, 0, stream>>>(lengths, out_declen);
    {
        int n = Bn * En * Pn;
        cvt_kernel<<<(n + 255) / 256, 256, 0, stream>>>(feats, featsH, n);
    }
    cvt_kernel<<<(4 * Dn * (Dn + En) + 255) / 256, 256, 0, stream>>>(lstm_w_ih, wihH, 4 * Dn * (Dn + En));
    cvt_kernel<<<(4 * Dn * Dn + 255) / 256, 256, 0, stream>>>(lstm_w_hh, whhH, 4 * Dn * Dn);
    cvtT_kernel<<<(Dn * Dn + 255) / 256, 256, 0, stream>>>(U_w, UwTh, Dn, Dn);
    cvtT_kernel<<<(Dn * En + 255) / 256, 256, 0, stream>>>(f_beta_w, fbwTh, Dn, En);
    cvtT_kernel<<<(Dn * Vn + 255) / 256, 256, 0, stream>>>(fc_w, fcwTh, Dn, Vn);

    // ---- entire recurrence: one persistent cooperative kernel ----
    LoopParams lp;
    lp.WsH = WsH; lp.featsH = featsH; lp.wihH = wihH; lp.whhH = whhH;
    lp.UwTh = UwTh; lp.fbwTh = fbwTh; lp.fcwTh = fcwTh;
    lp.Ub = U_b; lp.fbb = f_beta_b; lp.fcb = fc_b;
    lp.vw = v_w; lp.vb = v_b;
    lp.bih = lstm_b_ih; lp.bhh = lstm_b_hh;
    lp.emb = emb;
    lp.captions = captions; lp.lengths = lengths;
    lp.hA = hA; lp.hB = hB; lp.cbuf = cbuf;
    lp.hU = hU; lp.gate = gate; lp.xctx = xctx; lp.esc = esc;
    lp.out_preds = out_preds; lp.out_alphas = out_alphas;

    void* kargs[] = { (void*)&lp };

    // Launch 512 WGs (2/CU) if the 512-variant is co-residency-safe, else 256 (1/CU).
    int maxb = 0;
    hipError_t oe = hipOccupancyMaxActiveBlocksPerMultiprocessor(&maxb, loop_kernel<512>, NTHR, 0);
    if (oe == hipSuccess && maxb >= 2) {
        hipLaunchCooperativeKernel((const void*)(loop_kernel<512>), dim3(512), dim3(NTHR),
                                   kargs, 0, stream);
    } else {
        hipLaunchCooperativeKernel((const void*)(loop_kernel<256>), dim3(256), dim3(NTHR),
                                   kargs, 0, stream);
    }
}

// Round 5
// 71680.658 us; speedup vs baseline: 1.0937x; 1.0937x over previous
//
#include <hip/hip_runtime.h>
#include <hip/hip_cooperative_groups.h>
#include <math.h>

// B=128, E=512, D=512, V=275, HW=24 -> P=576, T=300
static constexpr int Bn  = 128;
static constexpr int En  = 512;
static constexpr int Dn  = 512;
static constexpr int Vn  = 275;
static constexpr int Pn  = 576;
static constexpr int Tn  = 300;
static constexpr int TM1 = 299;

static constexpr int NWG    = 256;   // one workgroup per CU
static constexpr int NTHR   = 512;   // 8 waves per WG
static constexpr int NWAVES = NWG * (NTHR / 64);   // 2048

// derived phase mappings (NWG=256)
static constexpr int WPB_B = NWAVES / Bn;   // 16 phase-B waves per b
static constexpr int PPW   = Pn / WPB_B;    // 36 p per wave
static constexpr int WGPB  = NWG / Bn;      // 2 phase-C/D WGs per b
static constexpr int ROWS  = En / WGPB;     // 256 e-rows per WG
static constexpr int NIT   = ROWS / 8;      // 32 ctx iters
static constexpr int WPBG_E = NWAVES / 32;  // 64 phase-E waves per bgroup
static constexpr int DPW    = Dn / WPBG_E;  // 8 d per wave

typedef unsigned short ushort_t;
typedef unsigned int uint_t;

__device__ __forceinline__ float fast_tanh(float x) {
    float e2 = __expf(2.0f * x);
    return 1.0f - 2.0f / (e2 + 1.0f);
}
__device__ __forceinline__ float sigmoidf_(float x) {
    return 1.0f / (1.0f + __expf(-x));
}
__device__ __forceinline__ float wave_reduce(float v) {
#pragma unroll
    for (int o = 32; o > 0; o >>= 1) v += __shfl_xor(v, o, 64);
    return v;
}
__device__ __forceinline__ ushort_t f2b(float x) {      // fp32 -> bf16 RNE
    uint_t u = __float_as_uint(x);
    u = (u + 0x7fffu + ((u >> 16) & 1u)) >> 16;
    return (ushort_t)u;
}
__device__ __forceinline__ float b2f(ushort_t u) {
    return __uint_as_float(((uint_t)u) << 16);
}
__device__ __forceinline__ void unpack8(uint4 q, float* f) {  // 8 bf16 (little-endian pairs)
    f[0] = __uint_as_float(q.x << 16); f[1] = __uint_as_float(q.x & 0xffff0000u);
    f[2] = __uint_as_float(q.y << 16); f[3] = __uint_as_float(q.y & 0xffff0000u);
    f[4] = __uint_as_float(q.z << 16); f[5] = __uint_as_float(q.z & 0xffff0000u);
    f[6] = __uint_as_float(q.w << 16); f[7] = __uint_as_float(q.w & 0xffff0000u);
}

// Fast grid barrier: bar[0]=arrival counter, bar[32]=generation (separate 128B line).
// Requires all NWG workgroups co-resident (cooperative launch).
__device__ __forceinline__ void gbar(uint_t* bar) {
    __syncthreads();   // drains vmcnt -> all WG writes are in L2 before the fence
    if (threadIdx.x == 0) {
        __threadfence();   // agent-scope release: L2 writeback visible across XCDs
        uint_t gen = __hip_atomic_load(&bar[32], __ATOMIC_RELAXED, __HIP_MEMORY_SCOPE_AGENT);
        uint_t n = __hip_atomic_fetch_add(&bar[0], 1u, __ATOMIC_ACQ_REL, __HIP_MEMORY_SCOPE_AGENT);
        if (n == (uint_t)(NWG - 1)) {
            __hip_atomic_store(&bar[0], 0u, __ATOMIC_RELAXED, __HIP_MEMORY_SCOPE_AGENT);
            __hip_atomic_store(&bar[32], gen + 1u, __ATOMIC_RELEASE, __HIP_MEMORY_SCOPE_AGENT);
        } else {
            while (__hip_atomic_load(&bar[32], __ATOMIC_ACQUIRE, __HIP_MEMORY_SCOPE_AGENT) == gen) {
                __builtin_amdgcn_s_sleep(8);
            }
        }
        __threadfence();   // acquire side: invalidate stale lines before re-reading data
    }
    __syncthreads();
}

// ---------------- one-time kernels ----------------

__global__ void mean_kernel(const float* __restrict__ feats, float* __restrict__ mean) {
    int w = blockIdx.x * 4 + (threadIdx.x >> 6);   // row in [0, B*E)
    int lane = threadIdx.x & 63;
    const float* row = feats + (size_t)w * Pn;
    float s = 0.f;
#pragma unroll
    for (int i = 0; i < 9; i++) s += row[lane + i * 64];
    s = wave_reduce(s);
    if (lane == 0) mean[w] = s * (1.0f / Pn);
}

__global__ void init_kernel(const float* __restrict__ mean,
                            const float* __restrict__ ihw, const float* __restrict__ ihb,
                            const float* __restrict__ icw, const float* __restrict__ icb,
                            float* __restrict__ h, float* __restrict__ c) {
    int b = blockIdx.x; int d = threadIdx.x;  // 512 threads
    const float* m = mean + b * En;
    float ah = ihb[d], ac = icb[d];
#pragma unroll 8
    for (int e = 0; e < En; e++) {
        float mv = m[e];
        ah += mv * ihw[e * Dn + d];
        ac += mv * icw[e * Dn + d];
    }
    h[b * Dn + d] = ah;
    c[b * Dn + d] = ac;
}

// Ws[b,p,d] = sum_e feats[b,e,p] * W_w[e,d] + W_b[d]  -> bf16
__global__ void ws_kernel(const float* __restrict__ feats, const float* __restrict__ Ww,
                          const float* __restrict__ Wb, ushort_t* __restrict__ WsH) {
    int p = blockIdx.x, b = blockIdx.y, d = threadIdx.x;  // 512 threads
    const float* f = feats + (size_t)b * En * Pn + p;
    float acc = Wb[d];
#pragma unroll 8
    for (int e = 0; e < En; e++) acc += f[(size_t)e * Pn] * Ww[e * Dn + d];
    WsH[((size_t)b * Pn + p) * Dn + d] = f2b(acc);
}

__global__ void declen_kernel(const int* __restrict__ lengths, float* __restrict__ out_declen,
                              uint_t* __restrict__ bar) {
    int b = threadIdx.x;
    if (b < Bn) out_declen[b] = (float)(lengths[b] - 1);
    if (b < 64) bar[b] = 0u;   // zero barrier state (counter + generation lines)
}

// fp32 -> bf16 straight copy
__global__ void cvt_kernel(const float* __restrict__ src, ushort_t* __restrict__ dst, int n) {
    int idx = blockIdx.x * 256 + threadIdx.x;
    if (idx < n) dst[idx] = f2b(src[idx]);
}

// transpose + cvt: src[rows][cols] fp32 -> dst[cols][rows] bf16
__global__ void cvtT_kernel(const float* __restrict__ src, ushort_t* __restrict__ dst,
                            int rows, int cols) {
    int idx = blockIdx.x * 256 + threadIdx.x;
    if (idx >= rows * cols) return;
    int r = idx / cols, c = idx - r * cols;
    dst[(size_t)c * rows + r] = f2b(src[idx]);
}

// ---------------- persistent cooperative loop kernel ----------------

struct LoopParams {
    const ushort_t* WsH;
    const ushort_t* featsH;
    const ushort_t* wihH;
    const ushort_t* whhH;
    const ushort_t* UwTh;
    const ushort_t* fbwTh;
    const ushort_t* fcwTh;
    const float* Ub;  const float* fbb; const float* fcb;
    const float* vw;  const float* vb;
    const float* bih; const float* bhh;
    const float* emb;
    const int* captions; const int* lengths;
    float* hA; float* hB; float* cbuf;
    float* hU; float* gate; float* xctx; float* esc;
    float* out_preds; float* out_alphas;
    uint_t* bar;
};

__global__ __launch_bounds__(NTHR, 2) void loop_kernel(LoopParams p) {
    const int tid  = threadIdx.x;
    const int lane = tid & 63;
    const int wwg  = tid >> 6;                   // wave in WG [0,8)
    const int wg   = blockIdx.x;                 // [0,256)
    const int wv   = wg * (NTHR / 64) + wwg;     // global wave [0,2048)

    __shared__ float s_alpha[Pn];
    __shared__ float s_red[16];

    for (int tau = 0; tau <= TM1; ++tau) {
        const float* hin  = (tau & 1) ? p.hB : p.hA;
        float*       hout = (tau & 1) ? p.hA : p.hB;

        // ---- phase A: hU = h@U, gate = sigmoid(h@f_beta), preds(t=tau-1) = h@fc ----
        {
            const float4* h4 = (const float4*)hin;
            for (int it = wv; it < 32 * 325; it += NWAVES) {
                int bg = it / 325, jg = it - bg * 325;
                int j0 = jg * 4;
                if (tau == 0 && j0 >= 1024) continue;   // no preds at first step
                if (tau == TM1 && j0 < 1024) continue;  // final pass: preds only
                float4 hv[4][2];
#pragma unroll
                for (int i = 0; i < 4; i++) {
                    int basei = (bg * 4 + i) * 128 + 2 * lane;
                    hv[i][0] = h4[basei]; hv[i][1] = h4[basei + 1];
                }
#pragma unroll
                for (int jj = 0; jj < 4; jj++) {
                    int j = j0 + jj;
                    const ushort_t* row;
                    if (j < 512) row = p.UwTh + (size_t)j * 512;
                    else if (j < 1024) row = p.fbwTh + (size_t)(j - 512) * 512;
                    else { if (j - 1024 >= Vn) continue; row = p.fcwTh + (size_t)(j - 1024) * 512; }
                    uint4 q = *(const uint4*)(row + 8 * lane);
                    float w8[8]; unpack8(q, w8);
                    float a[4];
#pragma unroll
                    for (int i = 0; i < 4; i++) {
                        a[i] = hv[i][0].x * w8[0] + hv[i][0].y * w8[1] + hv[i][0].z * w8[2] + hv[i][0].w * w8[3]
                             + hv[i][1].x * w8[4] + hv[i][1].y * w8[5] + hv[i][1].z * w8[6] + hv[i][1].w * w8[7];
                    }
#pragma unroll
                    for (int o = 32; o > 0; o >>= 1) {
#pragma unroll
                        for (int i = 0; i < 4; i++) a[i] += __shfl_xor(a[i], o, 64);
                    }
                    if (lane == 0) {
                        if (j < 512) {
                            float bias = p.Ub[j];
#pragma unroll
                            for (int i = 0; i < 4; i++) p.hU[(bg * 4 + i) * Dn + j] = a[i] + bias;
                        } else if (j < 1024) {
                            int e = j - 512;
                            float bias = p.fbb[e];
#pragma unroll
                            for (int i = 0; i < 4; i++) p.gate[(bg * 4 + i) * En + e] = sigmoidf_(a[i] + bias);
                        } else if (tau > 0) {
                            int v = j - 1024;
                            int t = tau - 1;
                            float bias = p.fcb[v];
#pragma unroll
                            for (int i = 0; i < 4; i++) {
                                int b = bg * 4 + i;
                                int dec = p.lengths[b] - 1;
                                p.out_preds[((size_t)b * TM1 + t) * Vn + v] = (t < dec) ? (a[i] + bias) : 0.f;
                            }
                        }
                    }
                }
            }
        }
        if (tau == TM1) break;
        gbar(p.bar);

        // ---- phase B: e[b,p] = sum_d tanh(Ws + hU)*v + vb ----
        // wave -> (b, PPW consecutive p). hU/v hoisted; depth-2 prefetch.
        {
            int b  = wv / WPB_B;
            int p0 = (wv % WPB_B) * PPW;
            const float4* hu4 = (const float4*)(p.hU + (b << 9));
            float4 h0 = hu4[2 * lane], h1 = hu4[2 * lane + 1];
            const float4* v4 = (const float4*)p.vw;
            float4 vv0 = v4[2 * lane], vv1 = v4[2 * lane + 1];
            float vb0 = p.vb[0];
            const ushort_t* base = p.WsH + ((size_t)b * Pn + p0) * Dn + 8 * lane;
            uint4 q0 = *(const uint4*)base;
            uint4 q1 = *(const uint4*)(base + Dn);
            for (int k = 0; k < PPW; ++k) {
                uint4 q2 = q0;
                if (k < PPW - 2) q2 = *(const uint4*)(base + (size_t)(k + 2) * Dn);
                float w8[8]; unpack8(q0, w8);
                float acc;
                acc  = fast_tanh(w8[0] + h0.x) * vv0.x;
                acc += fast_tanh(w8[1] + h0.y) * vv0.y;
                acc += fast_tanh(w8[2] + h0.z) * vv0.z;
                acc += fast_tanh(w8[3] + h0.w) * vv0.w;
                acc += fast_tanh(w8[4] + h1.x) * vv1.x;
                acc += fast_tanh(w8[5] + h1.y) * vv1.y;
                acc += fast_tanh(w8[6] + h1.z) * vv1.z;
                acc += fast_tanh(w8[7] + h1.w) * vv1.w;
                acc = wave_reduce(acc);
                if (lane == 0) p.esc[b * Pn + p0 + k] = acc + vb0;
                q0 = q1; q1 = q2;
            }
        }
        gbar(p.bar);

        // ---- phase C+D: softmax(alpha in LDS) + ctx, 2 WGs per b ----
        {
            int b = wg / WGPB, part = wg % WGPB;
            float v0 = p.esc[b * Pn + tid];
            float v1 = (tid < 64) ? p.esc[b * Pn + 512 + tid] : -3.0e38f;
            float m = fmaxf(v0, v1);
#pragma unroll
            for (int o = 32; o > 0; o >>= 1) m = fmaxf(m, __shfl_xor(m, o, 64));
            if (lane == 0) s_red[wwg] = m;
            __syncthreads();
            if (tid == 0) {
                float mm = s_red[0];
                for (int i = 1; i < 8; i++) mm = fmaxf(mm, s_red[i]);
                s_red[8] = mm;
            }
            __syncthreads();
            float mx  = s_red[8];
            float ex0 = __expf(v0 - mx);
            float ex1 = (tid < 64) ? __expf(v1 - mx) : 0.f;
            float ssum = wave_reduce(ex0 + ex1);
            if (lane == 0) s_red[wwg] = ssum;
            __syncthreads();
            if (tid == 0) {
                float ss = 0.f;
                for (int i = 0; i < 8; i++) ss += s_red[i];
                s_red[9] = 1.0f / ss;
            }
            __syncthreads();
            float inv = s_red[9];
            float a0 = ex0 * inv;
            float a1 = ex1 * inv;
            s_alpha[tid] = a0;
            if (tid < 64) s_alpha[512 + tid] = a1;
            if (part == 0) {
                int dec = p.lengths[b] - 1;
                float keep = (tau < dec) ? 1.f : 0.f;
                size_t rb = ((size_t)b * TM1 + tau) * Pn;
                p.out_alphas[rb + tid] = a0 * keep;
                if (tid < 64) p.out_alphas[rb + 512 + tid] = a1 * keep;
            }
            __syncthreads();
            // ctx rows: each WG does ROWS e-rows of its b; depth-1 prefetch
            const float4* a4 = (const float4*)s_alpha;
            float4 aa0 = a4[2 * lane], aa1 = a4[2 * lane + 1];
            float atail = s_alpha[512 + lane];
            int e0 = part * ROWS + wwg;
            const ushort_t* fbase = p.featsH + ((size_t)(b * En + e0)) * Pn;
            uint4 q = *(const uint4*)(fbase + 8 * lane);
            float tl = b2f(fbase[512 + lane]);
            for (int i = 0; i < NIT; ++i) {
                uint4 qn = q; float tn = tl;
                if (i < NIT - 1) {
                    const ushort_t* fn = fbase + (size_t)(i + 1) * 8 * Pn;
                    qn = *(const uint4*)(fn + 8 * lane);
                    tn = b2f(fn[512 + lane]);
                }
                float w8[8]; unpack8(q, w8);
                float s;
                s  = w8[0] * aa0.x + w8[1] * aa0.y + w8[2] * aa0.z + w8[3] * aa0.w;
                s += w8[4] * aa1.x + w8[5] * aa1.y + w8[6] * aa1.z + w8[7] * aa1.w;
                s += tl * atail;
                s = wave_reduce(s);
                if (lane == 0) {
                    int e = e0 + i * 8;
                    p.xctx[b * En + e] = p.gate[b * En + e] * s;
                }
                q = qn; tl = tn;
            }
        }
        gbar(p.bar);

        // ---- phase E: LSTM cell. Wave owns (bg, DPW consecutive d); activations
        // loaded to registers ONCE per step, only weights stream per-d. ----
        {
            int bg = wv / WPBG_E;
            int d0 = (wv % WPBG_E) * DPW;
            float4 u[4][6];   // per batch: emb0,emb1, gctx0,gctx1, h0,h1
#pragma unroll
            for (int i = 0; i < 4; i++) {
                int b = bg * 4 + i;
                int tok = p.captions[b * Tn + tau];
                const float4* e4 = (const float4*)(p.emb + (size_t)tok * Dn);
                const float4* x4 = (const float4*)(p.xctx + b * En);
                const float4* h4 = (const float4*)(hin + b * Dn);
                u[i][0] = e4[2 * lane]; u[i][1] = e4[2 * lane + 1];
                u[i][2] = x4[2 * lane]; u[i][3] = x4[2 * lane + 1];
                u[i][4] = h4[2 * lane]; u[i][5] = h4[2 * lane + 1];
            }
            for (int dd = 0; dd < DPW; ++dd) {
                int d = d0 + dd;
                float acc[4][4];
#pragma unroll
                for (int g = 0; g < 4; g++)
#pragma unroll
                    for (int i = 0; i < 4; i++) acc[g][i] = 0.f;
#pragma unroll
                for (int g = 0; g < 4; g++) {
                    int j = g * 512 + d;
                    const ushort_t* wi = p.wihH + (size_t)j * 1024;
                    const ushort_t* wh = p.whhH + (size_t)j * 512;
                    uint4 q0 = *(const uint4*)(wi + 8 * lane);
                    uint4 q1 = *(const uint4*)(wi + 512 + 8 * lane);
                    uint4 q2 = *(const uint4*)(wh + 8 * lane);
                    float wa[8], wb[8], wc[8];
                    unpack8(q0, wa); unpack8(q1, wb); unpack8(q2, wc);
#pragma unroll
                    for (int i = 0; i < 4; i++) {
                        float s;
                        s  = u[i][0].x * wa[0] + u[i][0].y * wa[1] + u[i][0].z * wa[2] + u[i][0].w * wa[3];
                        s += u[i][1].x * wa[4] + u[i][1].y * wa[5] + u[i][1].z * wa[6] + u[i][1].w * wa[7];
                        s += u[i][2].x * wb[0] + u[i][2].y * wb[1] + u[i][2].z * wb[2] + u[i][2].w * wb[3];
                        s += u[i][3].x * wb[4] + u[i][3].y * wb[5] + u[i][3].z * wb[6] + u[i][3].w * wb[7];
                        s += u[i][4].x * wc[0] + u[i][4].y * wc[1] + u[i][4].z * wc[2] + u[i][4].w * wc[3];
                        s += u[i][5].x * wc[4] + u[i][5].y * wc[5] + u[i][5].z * wc[6] + u[i][5].w * wc[7];
                        acc[g][i] += s;
                    }
                }
#pragma unroll
                for (int o = 32; o > 0; o >>= 1) {
#pragma unroll
                    for (int g = 0; g < 4; g++)
#pragma unroll
                        for (int i = 0; i < 4; i++) acc[g][i] += __shfl_xor(acc[g][i], o, 64);
                }
                if (lane == 0) {
                    float bi  = p.bih[d] + p.bhh[d];
                    float bf  = p.bih[512 + d] + p.bhh[512 + d];
                    float bgg = p.bih[1024 + d] + p.bhh[1024 + d];
                    float bo  = p.bih[1536 + d] + p.bhh[1536 + d];
#pragma unroll
                    for (int i = 0; i < 4; i++) {
                        int b = bg * 4 + i;
                        float ig = sigmoidf_(acc[0][i] + bi);
                        float fg = sigmoidf_(acc[1][i] + bf);
                        float gg = fast_tanh(acc[2][i] + bgg);
                        float og = sigmoidf_(acc[3][i] + bo);
                        float cn = fg * p.cbuf[b * Dn + d] + ig * gg;
                        p.cbuf[b * Dn + d] = cn;
                        hout[b * Dn + d] = og * fast_tanh(cn);
                    }
                }
            }
        }
        gbar(p.bar);
    }
}

extern "C" void kernel_launch(void* const* d_in, const int* in_sizes, int n_in,
                              void* d_out, int out_size, void* d_ws, size_t ws_size,
                              hipStream_t stream) {
    const float* feats    = (const float*)d_in[0];
    const int*   captions = (const int*)d_in[1];
    const int*   lengths  = (const int*)d_in[2];
    const float* U_w      = (const float*)d_in[3];
    const float* U_b      = (const float*)d_in[4];
    const float* W_w      = (const float*)d_in[5];
    const float* W_b      = (const float*)d_in[6];
    const float* v_w      = (const float*)d_in[7];
    const float* v_b      = (const float*)d_in[8];
    const float* init_h_w = (const float*)d_in[9];
    const float* init_h_b = (const float*)d_in[10];
    const float* init_c_w = (const float*)d_in[11];
    const float* init_c_b = (const float*)d_in[12];
    const float* f_beta_w = (const float*)d_in[13];
    const float* f_beta_b = (const float*)d_in[14];
    const float* fc_w     = (const float*)d_in[15];
    const float* fc_b     = (const float*)d_in[16];
    const float* emb      = (const float*)d_in[17];
    const float* lstm_w_ih = (const float*)d_in[18];
    const float* lstm_w_hh = (const float*)d_in[19];
    const float* lstm_b_ih = (const float*)d_in[20];
    const float* lstm_b_hh = (const float*)d_in[21];

    char* base = (char*)d_ws;
    size_t off = 0;
    ushort_t* WsH    = (ushort_t*)(base + off); off += (size_t)Bn * Pn * Dn * 2;   // 75.5 MB
    ushort_t* featsH = (ushort_t*)(base + off); off += (size_t)Bn * En * Pn * 2;   // 75.5 MB
    ushort_t* wihH   = (ushort_t*)(base + off); off += (size_t)4 * Dn * (Dn + En) * 2;
    ushort_t* whhH   = (ushort_t*)(base + off); off += (size_t)4 * Dn * Dn * 2;
    ushort_t* UwTh   = (ushort_t*)(base + off); off += (size_t)Dn * Dn * 2;
    ushort_t* fbwTh  = (ushort_t*)(base + off); off += (size_t)En * Dn * 2;
    ushort_t* fcwTh  = (ushort_t*)(base + off); off += (size_t)Vn * Dn * 2;
    float* mean  = (float*)(base + off); off += (size_t)Bn * En * 4;
    float* hA    = (float*)(base + off); off += (size_t)Bn * Dn * 4;
    float* hB    = (float*)(base + off); off += (size_t)Bn * Dn * 4;
    float* cbuf  = (float*)(base + off); off += (size_t)Bn * Dn * 4;
    float* hU    = (float*)(base + off); off += (size_t)Bn * Dn * 4;
    float* gate  = (float*)(base + off); off += (size_t)Bn * En * 4;
    float* xctx  = (float*)(base + off); off += (size_t)Bn * En * 4;
    float* esc   = (float*)(base + off); off += (size_t)Bn * Pn * 4;
    off = (off + 255) & ~(size_t)255;
    uint_t* bar  = (uint_t*)(base + off); off += 256;   // barrier state (2 cache lines)

    float* out_preds  = (float*)d_out;
    float* out_alphas = out_preds + (size_t)Bn * TM1 * Vn;
    float* out_declen = out_alphas + (size_t)Bn * TM1 * Pn;

    // ---- one-time precompute ----
    mean_kernel<<<Bn * En / 4, 256, 0, stream>>>(feats, mean);
    init_kernel<<<Bn, 512, 0, stream>>>(mean, init_h_w, init_h_b, init_c_w, init_c_b, hA, cbuf);
    ws_kernel<<<dim3(Pn, Bn), 512, 0, stream>>>(feats, W_w, W_b, WsH);
    declen_kernel<<<1, 128, 0, stream>>>(lengths, out_declen, bar);
    {
        int n = Bn * En * Pn;
        cvt_kernel<<<(n + 255) / 256, 256, 0, stream>>>(feats, featsH, n);
    }
    cvt_kernel<<<(4 * Dn * (Dn + En) + 255) / 256, 256, 0, stream>>>(lstm_w_ih, wihH, 4 * Dn * (Dn + En));
    cvt_kernel<<<(4 * Dn * Dn + 255) / 256, 256, 0, stream>>>(lstm_w_hh, whhH, 4 * Dn * Dn);
    cvtT_kernel<<<(Dn * Dn + 255) / 256, 256, 0, stream>>>(U_w, UwTh, Dn, Dn);
    cvtT_kernel<<<(Dn * En + 255) / 256, 256, 0, stream>>>(f_beta_w, fbwTh, Dn, En);
    cvtT_kernel<<<(Dn * Vn + 255) / 256, 256, 0, stream>>>(fc_w, fcwTh, Dn, Vn);

    // ---- entire recurrence: one persistent cooperative kernel ----
    LoopParams lp;
    lp.WsH = WsH; lp.featsH = featsH; lp.wihH = wihH; lp.whhH = whhH;
    lp.UwTh = UwTh; lp.fbwTh = fbwTh; lp.fcwTh = fcwTh;
    lp.Ub = U_b; lp.fbb = f_beta_b; lp.fcb = fc_b;
    lp.vw = v_w; lp.vb = v_b;
    lp.bih = lstm_b_ih; lp.bhh = lstm_b_hh;
    lp.emb = emb;
    lp.captions = captions; lp.lengths = lengths;
    lp.hA = hA; lp.hB = hB; lp.cbuf = cbuf;
    lp.hU = hU; lp.gate = gate; lp.xctx = xctx; lp.esc = esc;
    lp.out_preds = out_preds; lp.out_alphas = out_alphas;
    lp.bar = bar;

    void* kargs[] = { (void*)&lp };
    hipLaunchCooperativeKernel((const void*)loop_kernel, dim3(NWG), dim3(NTHR),
                               kargs, 0, stream);
}

// Round 6
// 66509.583 us; speedup vs baseline: 1.1787x; 1.0777x over previous
//
#include <hip/hip_runtime.h>
#include <math.h>

// B=128, E=512, D=512, V=275, HW=24 -> P=576, T=300
static constexpr int Bn  = 128;
static constexpr int En  = 512;
static constexpr int Dn  = 512;
static constexpr int Vn  = 275;
static constexpr int Pn  = 576;
static constexpr int Tn  = 300;
static constexpr int TM1 = 299;
static constexpr int NJ  = 512 + 512 + Vn;   // 1299 phase-A rows

typedef unsigned short ushort_t;
typedef unsigned int uint_t;

__device__ __forceinline__ float fast_tanh(float x) {
    float e2 = __expf(2.0f * x);
    return 1.0f - 2.0f / (e2 + 1.0f);
}
__device__ __forceinline__ float sigmoidf_(float x) {
    return 1.0f / (1.0f + __expf(-x));
}
__device__ __forceinline__ float wave_reduce(float v) {
#pragma unroll
    for (int o = 32; o > 0; o >>= 1) v += __shfl_xor(v, o, 64);
    return v;
}
__device__ __forceinline__ ushort_t f2b(float x) {      // fp32 -> bf16 RNE
    uint_t u = __float_as_uint(x);
    u = (u + 0x7fffu + ((u >> 16) & 1u)) >> 16;
    return (ushort_t)u;
}
__device__ __forceinline__ float b2f(ushort_t u) {
    return __uint_as_float(((uint_t)u) << 16);
}
__device__ __forceinline__ void unpack8(uint4 q, float* f) {  // 8 bf16 (little-endian pairs)
    f[0] = __uint_as_float(q.x << 16); f[1] = __uint_as_float(q.x & 0xffff0000u);
    f[2] = __uint_as_float(q.y << 16); f[3] = __uint_as_float(q.y & 0xffff0000u);
    f[4] = __uint_as_float(q.z << 16); f[5] = __uint_as_float(q.z & 0xffff0000u);
    f[6] = __uint_as_float(q.w << 16); f[7] = __uint_as_float(q.w & 0xffff0000u);
}

// ---------------- one-time kernels ----------------

__global__ void mean_kernel(const float* __restrict__ feats, float* __restrict__ mean) {
    int w = blockIdx.x * 4 + (threadIdx.x >> 6);   // row in [0, B*E)
    int lane = threadIdx.x & 63;
    const float* row = feats + (size_t)w * Pn;
    float s = 0.f;
#pragma unroll
    for (int i = 0; i < 9; i++) s += row[lane + i * 64];
    s = wave_reduce(s);
    if (lane == 0) mean[w] = s * (1.0f / Pn);
}

__global__ void init_kernel(const float* __restrict__ mean,
                            const float* __restrict__ ihw, const float* __restrict__ ihb,
                            const float* __restrict__ icw, const float* __restrict__ icb,
                            float* __restrict__ h, float* __restrict__ c) {
    int b = blockIdx.x; int d = threadIdx.x;  // 512 threads
    const float* m = mean + b * En;
    float ah = ihb[d], ac = icb[d];
#pragma unroll 8
    for (int e = 0; e < En; e++) {
        float mv = m[e];
        ah += mv * ihw[e * Dn + d];
        ac += mv * icw[e * Dn + d];
    }
    h[b * Dn + d] = ah;
    c[b * Dn + d] = ac;
}

// Ws[b,p,d] = sum_e feats[b,e,p] * W_w[e,d] + W_b[d]  -> bf16
__global__ void ws_kernel(const float* __restrict__ feats, const float* __restrict__ Ww,
                          const float* __restrict__ Wb, ushort_t* __restrict__ WsH) {
    int p = blockIdx.x, b = blockIdx.y, d = threadIdx.x;  // 512 threads
    const float* f = feats + (size_t)b * En * Pn + p;
    float acc = Wb[d];
#pragma unroll 8
    for (int e = 0; e < En; e++) acc += f[(size_t)e * Pn] * Ww[e * Dn + d];
    WsH[((size_t)b * Pn + p) * Dn + d] = f2b(acc);
}

__global__ void declen_kernel(const int* __restrict__ lengths, float* __restrict__ out_declen) {
    int b = threadIdx.x;
    if (b < Bn) out_declen[b] = (float)(lengths[b] - 1);
}

// fp32 -> bf16 straight copy
__global__ void cvt_kernel(const float* __restrict__ src, ushort_t* __restrict__ dst, int n) {
    int idx = blockIdx.x * 256 + threadIdx.x;
    if (idx < n) dst[idx] = f2b(src[idx]);
}

// transpose + cvt: src[rows][cols] fp32 -> dst[cols][rows] bf16
__global__ void cvtT_kernel(const float* __restrict__ src, ushort_t* __restrict__ dst,
                            int rows, int cols) {
    int idx = blockIdx.x * 256 + threadIdx.x;
    if (idx >= rows * cols) return;
    int r = idx / cols, c = idx - r * cols;
    dst[(size_t)c * rows + r] = f2b(src[idx]);
}

// ---------------- per-batch persistent kernel (no grid sync at all) ----------------

struct LoopParams {
    const ushort_t* WsH;
    const ushort_t* featsH;
    const ushort_t* wihH;
    const ushort_t* whhH;
    const ushort_t* UwTh;
    const ushort_t* fbwTh;
    const ushort_t* fcwTh;
    const float* Ub;  const float* fbb; const float* fcb;
    const float* vw;  const float* vb;
    const float* bih; const float* bhh;
    const float* emb;
    const int* captions; const int* lengths;
    const float* h0; const float* c0;
    float* out_preds; float* out_alphas;
};

// One 1024-thread WG per batch element. All per-step state in LDS; only
// __syncthreads between phases. Per-dot math identical to the verified
// multi-WG version (same lane->element mapping, same reduce, same bias order).
__global__ __launch_bounds__(1024) void loop_kernel(LoopParams p) {
    const int b    = blockIdx.x;
    const int tid  = threadIdx.x;
    const int lane = tid & 63;
    const int wwg  = tid >> 6;                 // wave in WG [0,16)

    __shared__ float s_h0[Dn];
    __shared__ float s_h1[Dn];
    __shared__ float s_c[Dn];
    __shared__ float s_hU[Dn];
    __shared__ float s_gate[En];
    __shared__ float s_xctx[En];
    __shared__ float s_esc[Pn];
    __shared__ float s_alpha[Pn];
    __shared__ float s_red[16];

    const int dec = p.lengths[b] - 1;

    if (tid < Dn) {
        s_h0[tid] = p.h0[b * Dn + tid];
        s_c[tid]  = p.c0[b * Dn + tid];
    }
    __syncthreads();

    for (int tau = 0; tau <= TM1; ++tau) {
        const float* hin_s = (tau & 1) ? s_h1 : s_h0;
        float*       hout_s = (tau & 1) ? s_h0 : s_h1;

        // ---- phase A: hU(j<512), gate(j<1024), preds(j>=1024, t=tau-1) ----
        {
            const float4* h4 = (const float4*)hin_s;
            float4 hv0 = h4[2 * lane], hv1 = h4[2 * lane + 1];
            const int jlo = (tau == TM1) ? 1024 : 0;
            const int jhi = (tau == 0) ? 1024 : NJ;
            for (int j0 = jlo + wwg * 4; j0 < jhi; j0 += 64) {
                float a[4];
#pragma unroll
                for (int jj = 0; jj < 4; jj++) {
                    int j = j0 + jj;
                    if (j >= jhi) { a[jj] = 0.f; continue; }
                    const ushort_t* row;
                    if (j < 512) row = p.UwTh + (size_t)j * 512;
                    else if (j < 1024) row = p.fbwTh + (size_t)(j - 512) * 512;
                    else row = p.fcwTh + (size_t)(j - 1024) * 512;
                    uint4 q = *(const uint4*)(row + 8 * lane);
                    float w8[8]; unpack8(q, w8);
                    a[jj] = hv0.x * w8[0] + hv0.y * w8[1] + hv0.z * w8[2] + hv0.w * w8[3]
                          + hv1.x * w8[4] + hv1.y * w8[5] + hv1.z * w8[6] + hv1.w * w8[7];
                }
#pragma unroll
                for (int o = 32; o > 0; o >>= 1) {
#pragma unroll
                    for (int jj = 0; jj < 4; jj++) a[jj] += __shfl_xor(a[jj], o, 64);
                }
                if (lane == 0) {
#pragma unroll
                    for (int jj = 0; jj < 4; jj++) {
                        int j = j0 + jj;
                        if (j >= jhi) continue;
                        if (j < 512) {
                            s_hU[j] = a[jj] + p.Ub[j];
                        } else if (j < 1024) {
                            int e = j - 512;
                            s_gate[e] = sigmoidf_(a[jj] + p.fbb[e]);
                        } else {
                            int v = j - 1024;
                            int t = tau - 1;
                            p.out_preds[((size_t)b * TM1 + t) * Vn + v] =
                                (t < dec) ? (a[jj] + p.fcb[v]) : 0.f;
                        }
                    }
                }
            }
        }
        if (tau == TM1) break;
        __syncthreads();

        // ---- phase B: esc[p] = sum_d tanh(Ws + hU)*v + vb, 36 rows/wave ----
        {
            int p0 = wwg * 36;
            const float4* hu4 = (const float4*)s_hU;
            float4 h0 = hu4[2 * lane], h1 = hu4[2 * lane + 1];
            const float4* v4 = (const float4*)p.vw;
            float4 vv0 = v4[2 * lane], vv1 = v4[2 * lane + 1];
            float vb0 = p.vb[0];
            const ushort_t* base = p.WsH + ((size_t)b * Pn + p0) * Dn + 8 * lane;
            uint4 q0 = *(const uint4*)base;
            uint4 q1 = *(const uint4*)(base + Dn);
            for (int k = 0; k < 36; ++k) {
                uint4 q2 = q0;
                if (k < 34) q2 = *(const uint4*)(base + (size_t)(k + 2) * Dn);
                float w8[8]; unpack8(q0, w8);
                float acc;
                acc  = fast_tanh(w8[0] + h0.x) * vv0.x;
                acc += fast_tanh(w8[1] + h0.y) * vv0.y;
                acc += fast_tanh(w8[2] + h0.z) * vv0.z;
                acc += fast_tanh(w8[3] + h0.w) * vv0.w;
                acc += fast_tanh(w8[4] + h1.x) * vv1.x;
                acc += fast_tanh(w8[5] + h1.y) * vv1.y;
                acc += fast_tanh(w8[6] + h1.z) * vv1.z;
                acc += fast_tanh(w8[7] + h1.w) * vv1.w;
                acc = wave_reduce(acc);
                if (lane == 0) s_esc[p0 + k] = acc + vb0;
                q0 = q1; q1 = q2;
            }
        }
        __syncthreads();

        // ---- phase C: softmax over 576 (waves 0-7 carry values, 8-15 inert) ----
        {
            float v0 = (tid < 512) ? s_esc[tid] : -3.0e38f;
            float v1 = (tid < 64) ? s_esc[512 + tid] : -3.0e38f;
            float m = fmaxf(v0, v1);
#pragma unroll
            for (int o = 32; o > 0; o >>= 1) m = fmaxf(m, __shfl_xor(m, o, 64));
            if (lane == 0 && wwg < 8) s_red[wwg] = m;
            __syncthreads();
            if (tid == 0) {
                float mm = s_red[0];
                for (int i = 1; i < 8; i++) mm = fmaxf(mm, s_red[i]);
                s_red[8] = mm;
            }
            __syncthreads();
            float mx  = s_red[8];
            float ex0 = (tid < 512) ? __expf(v0 - mx) : 0.f;
            float ex1 = (tid < 64) ? __expf(v1 - mx) : 0.f;
            float ssum = wave_reduce(ex0 + ex1);
            if (lane == 0 && wwg < 8) s_red[wwg] = ssum;
            __syncthreads();
            if (tid == 0) {
                float ss = 0.f;
                for (int i = 0; i < 8; i++) ss += s_red[i];
                s_red[9] = 1.0f / ss;
            }
            __syncthreads();
            float inv = s_red[9];
            float keep = (tau < dec) ? 1.f : 0.f;
            size_t rb = ((size_t)b * TM1 + tau) * Pn;
            if (tid < 512) {
                float a0 = ex0 * inv;
                s_alpha[tid] = a0;
                p.out_alphas[rb + tid] = a0 * keep;
            }
            if (tid < 64) {
                float a1 = ex1 * inv;
                s_alpha[512 + tid] = a1;
                p.out_alphas[rb + 512 + tid] = a1 * keep;
            }
        }
        __syncthreads();

        // ---- phase D: xctx[e] = gate[e] * (alpha . featsH[b,e,:]), 32 rows/wave ----
        {
            const float4* a4 = (const float4*)s_alpha;
            float4 aa0 = a4[2 * lane], aa1 = a4[2 * lane + 1];
            float atail = s_alpha[512 + lane];
            const ushort_t* fbase = p.featsH + ((size_t)(b * En + wwg)) * Pn;
            uint4 q = *(const uint4*)(fbase + 8 * lane);
            float tl = b2f(fbase[512 + lane]);
            for (int i = 0; i < 32; ++i) {
                uint4 qn = q; float tn = tl;
                if (i < 31) {
                    const ushort_t* fn = fbase + (size_t)(i + 1) * 16 * Pn;
                    qn = *(const uint4*)(fn + 8 * lane);
                    tn = b2f(fn[512 + lane]);
                }
                float w8[8]; unpack8(q, w8);
                float s;
                s  = w8[0] * aa0.x + w8[1] * aa0.y + w8[2] * aa0.z + w8[3] * aa0.w;
                s += w8[4] * aa1.x + w8[5] * aa1.y + w8[6] * aa1.z + w8[7] * aa1.w;
                s += tl * atail;
                s = wave_reduce(s);
                if (lane == 0) {
                    int e = wwg + i * 16;
                    s_xctx[e] = s_gate[e] * s;
                }
                q = qn; tl = tn;
            }
        }
        __syncthreads();

        // ---- phase E: LSTM cell, 32 d/wave ----
        {
            int d0 = wwg * 32;
            int tok = p.captions[b * Tn + tau];
            const float4* e4 = (const float4*)(p.emb + (size_t)tok * Dn);
            const float4* x4 = (const float4*)s_xctx;
            const float4* h4 = (const float4*)hin_s;
            float4 u0 = e4[2 * lane], u1 = e4[2 * lane + 1];
            float4 u2 = x4[2 * lane], u3 = x4[2 * lane + 1];
            float4 u4 = h4[2 * lane], u5 = h4[2 * lane + 1];
            for (int dd = 0; dd < 32; ++dd) {
                int d = d0 + dd;
                float acc[4];
#pragma unroll
                for (int g = 0; g < 4; g++) {
                    int j = g * 512 + d;
                    const ushort_t* wi = p.wihH + (size_t)j * 1024;
                    const ushort_t* wh = p.whhH + (size_t)j * 512;
                    uint4 q0 = *(const uint4*)(wi + 8 * lane);
                    uint4 q1 = *(const uint4*)(wi + 512 + 8 * lane);
                    uint4 q2 = *(const uint4*)(wh + 8 * lane);
                    float wa[8], wb[8], wc[8];
                    unpack8(q0, wa); unpack8(q1, wb); unpack8(q2, wc);
                    float s;
                    s  = u0.x * wa[0] + u0.y * wa[1] + u0.z * wa[2] + u0.w * wa[3];
                    s += u1.x * wa[4] + u1.y * wa[5] + u1.z * wa[6] + u1.w * wa[7];
                    s += u2.x * wb[0] + u2.y * wb[1] + u2.z * wb[2] + u2.w * wb[3];
                    s += u3.x * wb[4] + u3.y * wb[5] + u3.z * wb[6] + u3.w * wb[7];
                    s += u4.x * wc[0] + u4.y * wc[1] + u4.z * wc[2] + u4.w * wc[3];
                    s += u5.x * wc[4] + u5.y * wc[5] + u5.z * wc[6] + u5.w * wc[7];
                    acc[g] = s;
                }
#pragma unroll
                for (int o = 32; o > 0; o >>= 1) {
#pragma unroll
                    for (int g = 0; g < 4; g++) acc[g] += __shfl_xor(acc[g], o, 64);
                }
                if (lane == 0) {
                    float bi  = p.bih[d] + p.bhh[d];
                    float bf  = p.bih[512 + d] + p.bhh[512 + d];
                    float bgg = p.bih[1024 + d] + p.bhh[1024 + d];
                    float bo  = p.bih[1536 + d] + p.bhh[1536 + d];
                    float ig = sigmoidf_(acc[0] + bi);
                    float fg = sigmoidf_(acc[1] + bf);
                    float gg = fast_tanh(acc[2] + bgg);
                    float og = sigmoidf_(acc[3] + bo);
                    float cn = fg * s_c[d] + ig * gg;
                    s_c[d] = cn;
                    hout_s[d] = og * fast_tanh(cn);
                }
            }
        }
        __syncthreads();
    }
}

extern "C" void kernel_launch(void* const* d_in, const int* in_sizes, int n_in,
                              void* d_out, int out_size, void* d_ws, size_t ws_size,
                              hipStream_t stream) {
    const float* feats    = (const float*)d_in[0];
    const int*   captions = (const int*)d_in[1];
    const int*   lengths  = (const int*)d_in[2];
    const float* U_w      = (const float*)d_in[3];
    const float* U_b      = (const float*)d_in[4];
    const float* W_w      = (const float*)d_in[5];
    const float* W_b      = (const float*)d_in[6];
    const float* v_w      = (const float*)d_in[7];
    const float* v_b      = (const float*)d_in[8];
    const float* init_h_w = (const float*)d_in[9];
    const float* init_h_b = (const float*)d_in[10];
    const float* init_c_w = (const float*)d_in[11];
    const float* init_c_b = (const float*)d_in[12];
    const float* f_beta_w = (const float*)d_in[13];
    const float* f_beta_b = (const float*)d_in[14];
    const float* fc_w     = (const float*)d_in[15];
    const float* fc_b     = (const float*)d_in[16];
    const float* emb      = (const float*)d_in[17];
    const float* lstm_w_ih = (const float*)d_in[18];
    const float* lstm_w_hh = (const float*)d_in[19];
    const float* lstm_b_ih = (const float*)d_in[20];
    const float* lstm_b_hh = (const float*)d_in[21];

    char* base = (char*)d_ws;
    size_t off = 0;
    ushort_t* WsH    = (ushort_t*)(base + off); off += (size_t)Bn * Pn * Dn * 2;   // 75.5 MB
    ushort_t* featsH = (ushort_t*)(base + off); off += (size_t)Bn * En * Pn * 2;   // 75.5 MB
    ushort_t* wihH   = (ushort_t*)(base + off); off += (size_t)4 * Dn * (Dn + En) * 2;
    ushort_t* whhH   = (ushort_t*)(base + off); off += (size_t)4 * Dn * Dn * 2;
    ushort_t* UwTh   = (ushort_t*)(base + off); off += (size_t)Dn * Dn * 2;
    ushort_t* fbwTh  = (ushort_t*)(base + off); off += (size_t)En * Dn * 2;
    ushort_t* fcwTh  = (ushort_t*)(base + off); off += (size_t)Vn * Dn * 2;
    float* mean  = (float*)(base + off); off += (size_t)Bn * En * 4;
    float* hA    = (float*)(base + off); off += (size_t)Bn * Dn * 4;
    float* cbuf  = (float*)(base + off); off += (size_t)Bn * Dn * 4;

    float* out_preds  = (float*)d_out;
    float* out_alphas = out_preds + (size_t)Bn * TM1 * Vn;
    float* out_declen = out_alphas + (size_t)Bn * TM1 * Pn;

    // ---- one-time precompute ----
    mean_kernel<<<Bn * En / 4, 256, 0, stream>>>(feats, mean);
    init_kernel<<<Bn, 512, 0, stream>>>(mean, init_h_w, init_h_b, init_c_w, init_c_b, hA, cbuf);
    ws_kernel<<<dim3(Pn, Bn), 512, 0, stream>>>(feats, W_w, W_b, WsH);
    declen_kernel<<<1, 128, 0, stream>>>(lengths, out_declen);
    {
        int n = Bn * En * Pn;
        cvt_kernel<<<(n + 255) / 256, 256, 0, stream>>>(feats, featsH, n);
    }
    cvt_kernel<<<(4 * Dn * (Dn + En) + 255) / 256, 256, 0, stream>>>(lstm_w_ih, wihH, 4 * Dn * (Dn + En));
    cvt_kernel<<<(4 * Dn * Dn + 255) / 256, 256, 0, stream>>>(lstm_w_hh, whhH, 4 * Dn * Dn);
    cvtT_kernel<<<(Dn * Dn + 255) / 256, 256, 0, stream>>>(U_w, UwTh, Dn, Dn);
    cvtT_kernel<<<(Dn * En + 255) / 256, 256, 0, stream>>>(f_beta_w, fbwTh, Dn, En);
    cvtT_kernel<<<(Dn * Vn + 255) / 256, 256, 0, stream>>>(fc_w, fcwTh, Dn, Vn);

    // ---- entire recurrence: 128 independent per-batch WGs, plain launch ----
    LoopParams lp;
    lp.WsH = WsH; lp.featsH = featsH; lp.wihH = wihH; lp.whhH = whhH;
    lp.UwTh = UwTh; lp.fbwTh = fbwTh; lp.fcwTh = fcwTh;
    lp.Ub = U_b; lp.fbb = f_beta_b; lp.fcb = fc_b;
    lp.vw = v_w; lp.vb = v_b;
    lp.bih = lstm_b_ih; lp.bhh = lstm_b_hh;
    lp.emb = emb;
    lp.captions = captions; lp.lengths = lengths;
    lp.h0 = hA; lp.c0 = cbuf;
    lp.out_preds = out_preds; lp.out_alphas = out_alphas;

    loop_kernel<<<Bn, 1024, 0, stream>>>(lp);
}